// Round 1
// baseline (238.305 us; speedup 1.0000x reference)
//
#include <hip/hip_runtime.h>

// Unfold (im2col) for x: [16, 64, 128, 128] f32, K=3, pad=1.
// out[b][c*9 + m][y*W + x] = x[b, c, y + m/3 - 1, x + m%3 - 1] (0 if OOB)
// out shape flat: 16 * 576 * 16384 f32 = 604 MB. Memory (write) bound.

__global__ __launch_bounds__(256) void unfold_kernel(
    const float* __restrict__ in, float* __restrict__ out, int total4) {
    constexpr int C = 64, H = 128, W = 128;
    constexpr int HW4 = (H * W) / 4;   // 4096 float4 per (b,cm) image plane
    constexpr int W4 = W / 4;          // 32 float4 per row

    const int stride = gridDim.x * blockDim.x;
    for (int i4 = blockIdx.x * blockDim.x + threadIdx.x; i4 < total4; i4 += stride) {
        int pos4 = i4 & (HW4 - 1);     // float4 index within plane
        int bcm  = i4 >> 12;           // (b*576 + c*9 + m)
        int y    = pos4 >> 5;          // pos4 / W4
        int x0   = (pos4 & (W4 - 1)) << 2;

        int b  = bcm / 576;
        int cm = bcm - b * 576;
        int c  = cm / 9;
        int m  = cm - c * 9;
        int di = m / 3 - 1;
        int dj = m - (m / 3) * 3 - 1;

        int row = y + di;
        float4 v = make_float4(0.f, 0.f, 0.f, 0.f);
        if ((unsigned)row < (unsigned)H) {
            const float* src = in + (((b * C + c) * H + row) * W);
            int col = x0 + dj;
            v.x = ((unsigned)(col + 0) < (unsigned)W) ? src[col + 0] : 0.f;
            v.y = ((unsigned)(col + 1) < (unsigned)W) ? src[col + 1] : 0.f;
            v.z = ((unsigned)(col + 2) < (unsigned)W) ? src[col + 2] : 0.f;
            v.w = ((unsigned)(col + 3) < (unsigned)W) ? src[col + 3] : 0.f;
        }
        reinterpret_cast<float4*>(out)[i4] = v;
    }
}

extern "C" void kernel_launch(void* const* d_in, const int* in_sizes, int n_in,
                              void* d_out, int out_size, void* d_ws, size_t ws_size,
                              hipStream_t stream) {
    const float* in = (const float*)d_in[0];
    float* out = (float*)d_out;
    int total4 = out_size / 4;  // out_size = 150,994,944, divisible by 4
    int block = 256;
    int grid = (total4 + block - 1) / block;
    if (grid > 2048) grid = 2048;
    unfold_kernel<<<grid, block, 0, stream>>>(in, out, total4);
}

// Round 3
// 112.465 us; speedup vs baseline: 2.1189x; 2.1189x over previous
//
#include <hip/hip_runtime.h>

// Unfold (im2col) x: [16, 64, 128, 128] f32, K=3, pad=1.
// out[(b*64+c)*9 + m][y][x] = in[b,c, y + m/3 - 1, x + m%3 - 1], 0 if OOB.
// Write-BW-bound: 604 MB out + 64 MB in. Strategy: per (b,c,half-plane) block;
// per (row, di): 1 aligned float4 load + 2 edge scalars -> 3 shifted stores.

typedef float f32x4 __attribute__((ext_vector_type(4)));

__global__ __launch_bounds__(256) void unfold_kernel(
    const float* __restrict__ in, float* __restrict__ out) {
    constexpr int H = 128, W = 128;
    constexpr int W4 = W / 4;         // 32 float4 per row
    constexpr int PLANE4 = H * W / 4; // 4096 float4 per plane

    const int blk = blockIdx.x;      // 0 .. 2047
    const int half = blk & 1;
    const int bc = blk >> 1;         // b*64 + c

    const float* plane_in = in + (size_t)bc * (H * W);
    f32x4* plane_out = reinterpret_cast<f32x4*>(out) + (size_t)bc * 9 * PLANE4;

    const int tid = threadIdx.x;
    const int xq = tid & (W4 - 1);   // 0..31
    const int r0 = tid >> 5;         // 0..7
    const int x0 = xq << 2;

    for (int g = 0; g < 8; ++g) {             // 8 groups x 8 rows = 64 rows
        const int r = half * 64 + g * 8 + r0; // output row
        #pragma unroll
        for (int di = -1; di <= 1; ++di) {
            const int ry = r + di;
            f32x4 a = (f32x4)(0.f);
            float left = 0.f, right = 0.f;
            if ((unsigned)ry < (unsigned)H) {
                const float* row = plane_in + ry * W;
                a = reinterpret_cast<const f32x4*>(row)[xq];
                if (x0 > 0)     left  = row[x0 - 1];
                if (x0 < W - 4) right = row[x0 + 4];
            }
            f32x4 vm1; vm1.x = left; vm1.y = a.x; vm1.z = a.y; vm1.w = a.z; // dj=-1
            f32x4 vp1; vp1.x = a.y; vp1.y = a.z; vp1.z = a.w; vp1.w = right; // dj=+1
            const int mbase = (di + 1) * 3;
            const size_t o = (size_t)r * W4 + xq;
            __builtin_nontemporal_store(vm1, &plane_out[(size_t)(mbase + 0) * PLANE4 + o]);
            __builtin_nontemporal_store(a,   &plane_out[(size_t)(mbase + 1) * PLANE4 + o]);
            __builtin_nontemporal_store(vp1, &plane_out[(size_t)(mbase + 2) * PLANE4 + o]);
        }
    }
}

extern "C" void kernel_launch(void* const* d_in, const int* in_sizes, int n_in,
                              void* d_out, int out_size, void* d_ws, size_t ws_size,
                              hipStream_t stream) {
    const float* in = (const float*)d_in[0];
    float* out = (float*)d_out;
    // 16*64 planes x 2 halves = 2048 blocks, 256 threads each.
    unfold_kernel<<<2048, 256, 0, stream>>>(in, out);
}